// Round 9
// baseline (377.837 us; speedup 1.0000x reference)
//
#include <hip/hip_runtime.h>
#include <cfloat>
#include <math.h>

#define B2   2
#define BS4  4
#define NH   8
#define DH   64
#define DIM  512
#define NSEQ 1024
#define AH   16

typedef __attribute__((ext_vector_type(8))) short short8;
typedef __attribute__((ext_vector_type(4))) float floatx4;
typedef __attribute__((ext_vector_type(2))) float float2v;

// ---------- bf16 helpers ----------
__device__ inline unsigned short f2bf(float x) {
    unsigned int u = __float_as_uint(x);
    unsigned int r = (u + 0x7fffu + ((u >> 16) & 1u)) >> 16;
    return (unsigned short)r;
}
__device__ inline float bf2f(unsigned short h) {
    return __uint_as_float(((unsigned int)h) << 16);
}
__device__ inline void split2(float x, unsigned short& h, unsigned short& l) {
    h = f2bf(x);
    l = f2bf(x - bf2f(h));
}
// interleaved hi/lo address within a row: element k -> (k/8)*16 + (k%8); lo at +8
__device__ inline int il_addr(int k) { return ((k >> 3) << 4) + (k & 7); }

// packed fp32 fma (v_pk_fma_f32 on gfx90a+/gfx950)
__device__ inline float2v pk_fma(float2v a, float2v b, float2v c) {
#if __has_builtin(__builtin_elementwise_fma)
    return __builtin_elementwise_fma(a, b, c);
#else
    float2v r;
    r[0] = fmaf(a[0], b[0], c[0]);
    r[1] = fmaf(a[1], b[1], c[1]);
    return r;
#endif
}

// ============================================================
// NT MFMA core: C[M,N] += A[M,K] * B[N,K]^T, bf16 frags.
// SPLIT=true: hi/lo pairs, 3 MFMAs (≈fp32 precision).
// IL=true: hi/lo interleaved per 8-elem chunk (row stride 2K,
// Al = Ah+8).
// ============================================================
template<int MT, int NT_, bool SPLIT, bool IL>
__device__ inline void mfma_nt_core(
    const unsigned short* __restrict__ Ah, const unsigned short* __restrict__ Al,
    const unsigned short* __restrict__ Bh, const unsigned short* __restrict__ Bl,
    int K, int lda, int ldb, int arow, int bcol, floatx4 acc[MT][NT_])
{
    int lane = threadIdx.x & 63;
    int lr = lane & 15, lq = lane >> 4;
    for (int k0 = 0; k0 < K; k0 += 32) {
        const int ka = IL ? (k0 + lq * 8) * 2 : (k0 + lq * 8);
        short8 ah[MT], al[MT], bh[NT_], bl[NT_];
        #pragma unroll
        for (int mi = 0; mi < MT; ++mi) {
            size_t off = (size_t)(arow + mi * 16 + lr) * lda + ka;
            ah[mi] = *(const short8*)(Ah + off);
            if (SPLIT) al[mi] = *(const short8*)(Al + off);
        }
        #pragma unroll
        for (int ni = 0; ni < NT_; ++ni) {
            size_t off = (size_t)(bcol + ni * 16 + lr) * ldb + ka;
            bh[ni] = *(const short8*)(Bh + off);
            if (SPLIT) bl[ni] = *(const short8*)(Bl + off);
        }
        #pragma unroll
        for (int mi = 0; mi < MT; ++mi)
            #pragma unroll
            for (int ni = 0; ni < NT_; ++ni) {
                acc[mi][ni] = __builtin_amdgcn_mfma_f32_16x16x32_bf16(ah[mi], bh[ni], acc[mi][ni], 0, 0, 0);
                if (SPLIT) {
                    acc[mi][ni] = __builtin_amdgcn_mfma_f32_16x16x32_bf16(ah[mi], bl[ni], acc[mi][ni], 0, 0, 0);
                    acc[mi][ni] = __builtin_amdgcn_mfma_f32_16x16x32_bf16(al[mi], bh[ni], acc[mi][ni], 0, 0, 0);
                }
            }
    }
}

// ============================================================
// K1 (merged): blocks [0,4096): RMSNorm + sigmoid gates (xn
// interleaved hi/lo). blocks [4096,4608): weight conversion.
// ============================================================
#define NQKV (3 * DIM * NH * DH)     // 786432 = 1536 rows x 512 k
#define NOUT (DIM * NH * DH)         // 262144
__global__ __launch_bounds__(256) void k_prep(
    const float* __restrict__ x, const float* __restrict__ gamma,
    const float* __restrict__ wg, const float* __restrict__ bg,
    const float* __restrict__ wqkv, const float* __restrict__ wout,
    unsigned short* __restrict__ xn_il, float* __restrict__ gates,
    unsigned short* __restrict__ wq_il, unsigned short* __restrict__ wout_b)
{
    int tid = threadIdx.x;
    if (blockIdx.x >= BS4 * NSEQ) {
        int base = (blockIdx.x - BS4 * NSEQ) * 2048;
        #pragma unroll
        for (int e = 0; e < 8; ++e) {
            int i = base + e * 256 + tid;
            if (i < NQKV) {
                unsigned short hh, ll;
                split2(wqkv[i], hh, ll);
                int row = i >> 9, k = i & 511;
                size_t a = (size_t)row * (2 * DIM) + il_addr(k);
                wq_il[a] = hh; wq_il[a + 8] = ll;
            } else {
                wout_b[i - NQKV] = f2bf(wout[i - NQKV]);
            }
        }
        return;
    }
    int r = blockIdx.x;
    const float* xr = x + (size_t)r * DIM;
    float v0 = xr[tid];
    float v1 = xr[tid + 256];
    float ss = v0 * v0 + v1 * v1;
    #pragma unroll
    for (int off = 32; off > 0; off >>= 1) ss += __shfl_down(ss, off, 64);
    __shared__ float sc[4];
    __shared__ float scw[NH][4];
    if ((tid & 63) == 0) sc[tid >> 6] = ss;
    __syncthreads();
    float tot = sc[0] + sc[1] + sc[2] + sc[3];
    float rs = rsqrtf(tot * (1.0f / DIM) + 1e-5f);
    float n0 = v0 * rs * gamma[tid];
    float n1 = v1 * rs * gamma[tid + 256];
    size_t rb = (size_t)r * (2 * DIM);
    unsigned short hh, ll;
    split2(n0, hh, ll);
    int a0 = il_addr(tid);
    xn_il[rb + a0] = hh; xn_il[rb + a0 + 8] = ll;
    split2(n1, hh, ll);
    int a1 = il_addr(tid + 256);
    xn_il[rb + a1] = hh; xn_il[rb + a1 + 8] = ll;
    #pragma unroll
    for (int h = 0; h < NH; ++h) {
        float p = n0 * wg[h * DIM + tid] + n1 * wg[h * DIM + tid + 256];
        #pragma unroll
        for (int off = 32; off > 0; off >>= 1) p += __shfl_down(p, off, 64);
        if ((tid & 63) == 0) scw[h][tid >> 6] = p;
    }
    __syncthreads();
    if (tid < NH) {
        float g = scw[tid][0] + scw[tid][1] + scw[tid][2] + scw[tid][3] + bg[tid];
        gates[(size_t)r * NH + tid] = 1.0f / (1.0f + __expf(-g));
    }
}

// ============================================================
// K2: QKV projection, split-bf16 MFMA (interleaved operands).
// 1-wave blocks (64 thr), 64x64 tile/wave. Grid (24,64).
// ============================================================
__global__ __launch_bounds__(64) void k_qkv_mfma(
    const unsigned short* __restrict__ xn_il, const unsigned short* __restrict__ wq_il,
    unsigned short* __restrict__ q_il, unsigned short* __restrict__ k_il,
    unsigned short* __restrict__ vT_b)
{
    __shared__ unsigned short vs[64][68];    // [d][npos_local], padded
    int bx = blockIdx.x;
    int am = blockIdx.y * 64;
    int bn = bx * 64;
    floatx4 acc[4][4];
    #pragma unroll
    for (int mi = 0; mi < 4; ++mi)
        #pragma unroll
        for (int ni = 0; ni < 4; ++ni) acc[mi][ni] = (floatx4){0.f, 0.f, 0.f, 0.f};
    mfma_nt_core<4, 4, true, true>(xn_il, xn_il + 8, wq_il, wq_il + 8,
                                   DIM, 2 * DIM, 2 * DIM, am, bn, acc);
    int tid = threadIdx.x;
    int lane = tid & 63, lr = lane & 15, lq = lane >> 4;

    if (bx < 16) {
        const bool isq = (bx < 8);
        unsigned short* dst = isq ? q_il : k_il;
        const float scale = isq ? 8.0f : 1.0f;   // q * sqrt(dim_head)
        #pragma unroll
        for (int mi = 0; mi < 4; ++mi)
            #pragma unroll
            for (int ni = 0; ni < 4; ++ni)
                #pragma unroll
                for (int r = 0; r < 4; ++r) {
                    int row = am + mi * 16 + lq * 4 + r;
                    int col = bn + ni * 16 + lr;
                    int bs = row >> 10, npos = row & 1023;
                    int h = (col >> 6) & 7, d = col & 63;
                    size_t base = (((size_t)(bs * 8 + h)) * NSEQ + npos) * (2 * DH) + il_addr(d);
                    unsigned short hh, ll;
                    split2(acc[mi][ni][r] * scale, hh, ll);
                    dst[base] = hh; dst[base + 8] = ll;
                }
    } else {
        const int h = bx - 16;
        const int bs = (blockIdx.y * 64) >> 10;
        const int bh = bs * 8 + h;
        const int npos_base = (blockIdx.y * 64) & 1023;
        #pragma unroll
        for (int mi = 0; mi < 4; ++mi)
            #pragma unroll
            for (int ni = 0; ni < 4; ++ni)
                #pragma unroll
                for (int r = 0; r < 4; ++r) {
                    int nl  = mi * 16 + lq * 4 + r;
                    int dl2 = ni * 16 + lr;
                    vs[dl2][nl] = f2bf(acc[mi][ni][r]);
                }
        __syncthreads();
        #pragma unroll
        for (int it = 0; it < 8; ++it) {
            int d = it * 8 + (tid >> 3);
            int c8 = (tid & 7) * 8;
            unsigned short* dst = vT_b + ((size_t)bh * DH + d) * NSEQ + npos_base + c8;
            *(ulonglong2*)dst = *(ulonglong2*)&vs[d][c8];
        }
    }
}

// ============================================================
// K3: sim = q*k^T per bh, split-bf16 MFMA (interleaved operands),
// CAUSAL-TRIANGULAR: tiles with bn0 > am0+63 exit. 1-wave blocks.
// ============================================================
__global__ __launch_bounds__(64) void k_qk_mfma(
    const unsigned short* __restrict__ q_il, const unsigned short* __restrict__ k_il,
    float* __restrict__ sim_ws)
{
    __shared__ float cs[64][68];
    int am0 = blockIdx.y * 64;
    int bn0 = blockIdx.x * 64;
    if (bn0 > am0 + 63) return;
    int bh = blockIdx.z;
    int b_true = bh >> 4;
    int c = ((bh >> 3) & 1) * 8 + (bh & 7);
    const unsigned short* A = q_il + (size_t)bh * NSEQ * (2 * DH);
    const unsigned short* B = k_il + (size_t)bh * NSEQ * (2 * DH);
    floatx4 acc[4][4];
    #pragma unroll
    for (int mi = 0; mi < 4; ++mi)
        #pragma unroll
        for (int ni = 0; ni < 4; ++ni) acc[mi][ni] = (floatx4){0.f, 0.f, 0.f, 0.f};
    mfma_nt_core<4, 4, true, true>(A, A + 8, B, B + 8, DH, 2 * DH, 2 * DH, am0, bn0, acc);

    int tid = threadIdx.x;
    int lane = tid & 63, lr = lane & 15, lq = lane >> 4;
    #pragma unroll
    for (int mi = 0; mi < 4; ++mi)
        #pragma unroll
        for (int ni = 0; ni < 4; ++ni)
            #pragma unroll
            for (int r = 0; r < 4; ++r) {
                int lrow = mi * 16 + lq * 4 + r;
                int lcol = ni * 16 + lr;
                cs[lrow][lcol] = acc[mi][ni][r];
            }
    __syncthreads();
    int trow = tid >> 4;
    int tcol = (tid & 15) * 4;
    #pragma unroll
    for (int it = 0; it < 16; ++it) {
        int row = it * 4 + trow;
        float4 v4 = *(float4*)&cs[row][tcol];
        size_t gaddr = ((size_t)(b_true * NSEQ + am0 + row) * 16 + c) * NSEQ + bn0 + tcol;
        *(float4*)(sim_ws + gaddr) = v4;
    }
}

// ============================================================
// K4: pre-talk + mask + causal + softmax + post-talk.
// 512-thread blocks, thread owns 2 j: val[16] = 32 VGPRs (was 64)
// -> __launch_bounds__(512,8) pins VGPR<=64 -> 8 waves/SIMD max
// occupancy (was capped 50% at VGPR=72). Same phases/arithmetic
// as the verified r2 core; 2 barriers. attn2 goes to the COMPACT
// attn2c[b][c][i][j] buffer (2KB row stride) to fix k_av's 64KB
// A-stride channel conflict.
// ============================================================
__global__ __launch_bounds__(512, 8) void k_talk(
    const float* __restrict__ sim_ws, const int* __restrict__ mask,
    const float* __restrict__ wpre, const float* __restrict__ wpost,
    float* __restrict__ probs_out, unsigned short* __restrict__ attn2c)
{
    const int i = blockIdx.x;
    const int b = blockIdx.y;
    const int tid = threadIdx.x;
    const int wid = tid >> 6, lane = tid & 63;
    const int j0 = tid << 1;
    const size_t cstride = (size_t)NSEQ * NSEQ;
    const float* simrow = sim_ws + (size_t)(b * NSEQ + i) * (16 * NSEQ);

    const int2 mi0 = *(const int2*)(mask + (size_t)(b * 2 + 0) * NSEQ + j0);
    const int2 mi1 = *(const int2*)(mask + (size_t)(b * 2 + 1) * NSEQ + j0);
    bool mb[2][2];
    mb[0][0] = (mi0.x != 0) && (j0 + 0 <= i);
    mb[0][1] = (mi0.y != 0) && (j0 + 1 <= i);
    mb[1][0] = (mi1.x != 0) && (j0 + 0 <= i);
    mb[1][1] = (mi1.y != 0) && (j0 + 1 <= i);

    // ---- pre talking-heads, c streamed outermost ----
    float2v val[16];
    #pragma unroll
    for (int o = 0; o < 16; ++o) val[o] = (float2v){0.f, 0.f};
    #pragma unroll
    for (int c = 0; c < 16; ++c) {
        float2v r = *(const float2v*)(simrow + c * NSEQ + j0);
        #pragma unroll
        for (int o = 0; o < 16; ++o) {
            float w = wpre[o * 16 + c];
            val[o] = pk_fma((float2v){w, w}, r, val[o]);
        }
    }
    #pragma unroll
    for (int o = 0; o < 16; ++o) {
        const int s = o >> 3;
        if (!mb[s][0]) val[o][0] = -FLT_MAX;
        if (!mb[s][1]) val[o][1] = -FLT_MAX;
    }

    __shared__ float red_m[16][8];
    __shared__ float red_s[16][8];

    // ---- wave max per o -> LDS (barrier 1) ----
    #pragma unroll
    for (int o = 0; o < 16; ++o) {
        float m = fmaxf(val[o][0], val[o][1]);
        #pragma unroll
        for (int off = 32; off > 0; off >>= 1) m = fmaxf(m, __shfl_xor(m, off, 64));
        if (lane == 0) red_m[o][wid] = m;
    }
    __syncthreads();

    // ---- exp + wave sum per o -> LDS (barrier 2); each thread
    //      combines the 8 max partials itself (7 fmax < barrier) ----
    #pragma unroll
    for (int o = 0; o < 16; ++o) {
        float mx = fmaxf(fmaxf(fmaxf(red_m[o][0], red_m[o][1]), fmaxf(red_m[o][2], red_m[o][3])),
                         fmaxf(fmaxf(red_m[o][4], red_m[o][5]), fmaxf(red_m[o][6], red_m[o][7])));
        float e0 = __expf(val[o][0] - mx);
        float e1 = __expf(val[o][1] - mx);
        val[o][0] = e0; val[o][1] = e1;
        float s = e0 + e1;
        #pragma unroll
        for (int off = 32; off > 0; off >>= 1) s += __shfl_xor(s, off, 64);
        if (lane == 0) red_s[o][wid] = s;
    }
    __syncthreads();

    // ---- normalize + NT-store probs (output 1, [b*16+o][i][j]) ----
    #pragma unroll
    for (int o = 0; o < 16; ++o) {
        float tot = ((red_s[o][0] + red_s[o][1]) + (red_s[o][2] + red_s[o][3]))
                  + ((red_s[o][4] + red_s[o][5]) + (red_s[o][6] + red_s[o][7]));
        float inv = 1.0f / tot;
        val[o] *= (float2v){inv, inv};
        __builtin_nontemporal_store(val[o],
            (float2v*)(probs_out + (size_t)(b * 16 + o) * cstride + (size_t)i * NSEQ + j0));
    }

    // ---- post talking-heads -> bf16 attn2 (compact layout) ----
    #pragma unroll
    for (int o = 0; o < 16; ++o) {
        float2v a = (float2v){0.f, 0.f};
        #pragma unroll
        for (int c = 0; c < 16; ++c) {
            float w = wpost[o * 16 + c];
            a = pk_fma((float2v){w, w}, val[c], a);
        }
        unsigned int pk = (unsigned int)f2bf(a[0]) | ((unsigned int)f2bf(a[1]) << 16);
        *(unsigned int*)(attn2c + ((size_t)(b * 16 + o) * NSEQ + i) * NSEQ + j0) = pk;
    }
}

// ============================================================
// K5: gated = (attn2c @ v) * gate, plain bf16 MFMA (NT with vT).
// 2-wave K-split blocks (128 thr). attn2c row stride = NSEQ (2KB):
// a fragment's 16 lanes span 32KB, not 1MB. FULL K=NSEQ (r5 bug
// stays fixed: degenerate rows have mass beyond the diagonal).
// ============================================================
__global__ __launch_bounds__(128) void k_av_mfma(
    const unsigned short* __restrict__ attn2c, const unsigned short* __restrict__ vT_b,
    const float* __restrict__ gates, unsigned short* __restrict__ gated_b)
{
    __shared__ float cls[64][68];
    int bh = blockIdx.y;
    int bs = bh >> 3, h = bh & 7;
    int b_true = bh >> 4;
    int c = ((bh >> 3) & 1) * 8 + (bh & 7);
    int am = blockIdx.x * 64;
    int w = threadIdx.x >> 6;
    const unsigned short* Ah = attn2c + (size_t)(b_true * 16 + c) * NSEQ * NSEQ + w * 512;
    const unsigned short* Bh = vT_b + (size_t)bh * DH * NSEQ + w * 512;
    floatx4 acc[4][4];
    #pragma unroll
    for (int mi = 0; mi < 4; ++mi)
        #pragma unroll
        for (int ni = 0; ni < 4; ++ni) acc[mi][ni] = (floatx4){0.f, 0.f, 0.f, 0.f};
    mfma_nt_core<4, 4, false, false>(Ah, nullptr, Bh, nullptr, 512, NSEQ, NSEQ, am, 0, acc);
    int lane = threadIdx.x & 63, lr = lane & 15, lq = lane >> 4;
    if (w == 1) {
        #pragma unroll
        for (int mi = 0; mi < 4; ++mi)
            #pragma unroll
            for (int ni = 0; ni < 4; ++ni)
                #pragma unroll
                for (int r = 0; r < 4; ++r)
                    cls[mi * 16 + lq * 4 + r][ni * 16 + lr] = acc[mi][ni][r];
    }
    __syncthreads();
    if (w == 0) {
        #pragma unroll
        for (int mi = 0; mi < 4; ++mi)
            #pragma unroll
            for (int ni = 0; ni < 4; ++ni)
                #pragma unroll
                for (int r = 0; r < 4; ++r) {
                    int i = am + mi * 16 + lq * 4 + r;
                    int d = ni * 16 + lr;
                    float v = acc[mi][ni][r] + cls[mi * 16 + lq * 4 + r][ni * 16 + lr];
                    float g = gates[((size_t)bs * NSEQ + i) * NH + h];
                    gated_b[((size_t)bs * NSEQ + i) * DIM + h * DH + d] = f2bf(v * g);
                }
    }
}

// ============================================================
// K6: out = gated @ wout^T, plain bf16 MFMA. 2-wave K-split
// blocks (128 thr), halves of K=512.
// ============================================================
__global__ __launch_bounds__(128) void k_out_mfma(
    const unsigned short* __restrict__ gated_b, const unsigned short* __restrict__ wout_b,
    float* __restrict__ out)
{
    __shared__ float cls[64][68];
    int am = blockIdx.y * 64;
    int bn = blockIdx.x * 64;
    int w = threadIdx.x >> 6;
    floatx4 acc[4][4];
    #pragma unroll
    for (int mi = 0; mi < 4; ++mi)
        #pragma unroll
        for (int ni = 0; ni < 4; ++ni) acc[mi][ni] = (floatx4){0.f, 0.f, 0.f, 0.f};
    mfma_nt_core<4, 4, false, false>(gated_b + w * 256, nullptr, wout_b + w * 256, nullptr,
                                     256, DIM, DIM, am, bn, acc);
    int lane = threadIdx.x & 63, lr = lane & 15, lq = lane >> 4;
    if (w == 1) {
        #pragma unroll
        for (int mi = 0; mi < 4; ++mi)
            #pragma unroll
            for (int ni = 0; ni < 4; ++ni)
                #pragma unroll
                for (int r = 0; r < 4; ++r)
                    cls[mi * 16 + lq * 4 + r][ni * 16 + lr] = acc[mi][ni][r];
    }
    __syncthreads();
    if (w == 0) {
        #pragma unroll
        for (int mi = 0; mi < 4; ++mi)
            #pragma unroll
            for (int ni = 0; ni < 4; ++ni)
                #pragma unroll
                for (int r = 0; r < 4; ++r) {
                    int row = am + mi * 16 + lq * 4 + r;
                    int col = bn + ni * 16 + lr;
                    out[(size_t)row * DIM + col] =
                        acc[mi][ni][r] + cls[mi * 16 + lq * 4 + r][ni * 16 + lr];
                }
    }
}

// ============================================================
extern "C" void kernel_launch(void* const* d_in, const int* in_sizes, int n_in,
                              void* d_out, int out_size, void* d_ws, size_t ws_size,
                              hipStream_t stream)
{
    (void)in_sizes; (void)n_in; (void)out_size; (void)ws_size;

    const float* x     = (const float*)d_in[0];
    const int*   mask  = (const int*)  d_in[1];
    const float* gamma = (const float*)d_in[2];
    const float* wqkv  = (const float*)d_in[3];
    const float* wg    = (const float*)d_in[4];
    const float* bg    = (const float*)d_in[5];
    const float* wpre  = (const float*)d_in[6];
    const float* wpost = (const float*)d_in[7];
    const float* wout  = (const float*)d_in[8];

    float* out       = (float*)d_out;
    float* probs_out = out + (size_t)BS4 * NSEQ * DIM;   // output 1: [bs][h][i][j]

    // workspace layout (bytes)
    char* ws = (char*)d_ws;
    unsigned short* xn_il   = (unsigned short*)(ws);                 //  8 MB  [4096][1024]
    unsigned short* wq_il   = (unsigned short*)(ws + 8388608);       //  3 MB  [1536][1024]
    unsigned short* wout_b  = (unsigned short*)(ws + 11534336);      //  0.5 MB
    float*          gates   = (float*)         (ws + 12058624);      //  128 KB
    unsigned short* q_il    = (unsigned short*)(ws + 12189696);      //  8 MB  [16][1024][128]
    unsigned short* k_il    = (unsigned short*)(ws + 20578304);      //  8 MB
    unsigned short* vT_b    = (unsigned short*)(ws + 28966912);      //  4 MB
    unsigned short* gated_b = (unsigned short*)(ws + 33161216);      //  4 MB
    float*          sim_ws  = (float*)         (ws + 37355520);      // 128 MB interleaved [b][i][c][j]
    unsigned short* attn2c  = (unsigned short*)(ws + 171573248);     // 64 MB  [b][c][i][j]

    k_prep<<<dim3(BS4 * NSEQ + 512), dim3(256), 0, stream>>>(
        x, gamma, wg, bg, wqkv, wout, xn_il, gates, wq_il, wout_b);
    k_qkv_mfma<<<dim3(24, 64), dim3(64), 0, stream>>>(xn_il, wq_il, q_il, k_il, vT_b);
    k_qk_mfma<<<dim3(16, 16, 32), dim3(64), 0, stream>>>(q_il, k_il, sim_ws);
    k_talk<<<dim3(NSEQ, B2), dim3(512), 0, stream>>>(sim_ws, mask, wpre, wpost, probs_out, attn2c);
    k_av_mfma<<<dim3(16, 32), dim3(128), 0, stream>>>(attn2c, vT_b, gates, gated_b);
    k_out_mfma<<<dim3(8, 64), dim3(128), 0, stream>>>(gated_b, wout_b, out);
}

// Round 11
// 375.286 us; speedup vs baseline: 1.0068x; 1.0068x over previous
//
#include <hip/hip_runtime.h>
#include <cfloat>
#include <math.h>

#define B2   2
#define BS4  4
#define NH   8
#define DH   64
#define DIM  512
#define NSEQ 1024
#define AH   16

typedef __attribute__((ext_vector_type(8))) short short8;
typedef __attribute__((ext_vector_type(4))) float floatx4;
typedef __attribute__((ext_vector_type(2))) float float2v;

// ---------- bf16 helpers ----------
__device__ inline unsigned short f2bf(float x) {
    unsigned int u = __float_as_uint(x);
    unsigned int r = (u + 0x7fffu + ((u >> 16) & 1u)) >> 16;
    return (unsigned short)r;
}
__device__ inline float bf2f(unsigned short h) {
    return __uint_as_float(((unsigned int)h) << 16);
}
__device__ inline void split2(float x, unsigned short& h, unsigned short& l) {
    h = f2bf(x);
    l = f2bf(x - bf2f(h));
}
// interleaved hi/lo address within a row: element k -> (k/8)*16 + (k%8); lo at +8
__device__ inline int il_addr(int k) { return ((k >> 3) << 4) + (k & 7); }

// packed fp32 fma (v_pk_fma_f32 on gfx90a+/gfx950)
__device__ inline float2v pk_fma(float2v a, float2v b, float2v c) {
#if __has_builtin(__builtin_elementwise_fma)
    return __builtin_elementwise_fma(a, b, c);
#else
    float2v r;
    r[0] = fmaf(a[0], b[0], c[0]);
    r[1] = fmaf(a[1], b[1], c[1]);
    return r;
#endif
}

// ============================================================
// NT MFMA core: C[M,N] += A[M,K] * B[N,K]^T, bf16 frags.
// SPLIT=true: hi/lo pairs, 3 MFMAs (≈fp32 precision).
// IL=true: hi/lo interleaved per 8-elem chunk (row stride 2K,
// Al = Ah+8).
// ============================================================
template<int MT, int NT_, bool SPLIT, bool IL>
__device__ inline void mfma_nt_core(
    const unsigned short* __restrict__ Ah, const unsigned short* __restrict__ Al,
    const unsigned short* __restrict__ Bh, const unsigned short* __restrict__ Bl,
    int K, int lda, int ldb, int arow, int bcol, floatx4 acc[MT][NT_])
{
    int lane = threadIdx.x & 63;
    int lr = lane & 15, lq = lane >> 4;
    for (int k0 = 0; k0 < K; k0 += 32) {
        const int ka = IL ? (k0 + lq * 8) * 2 : (k0 + lq * 8);
        short8 ah[MT], al[MT], bh[NT_], bl[NT_];
        #pragma unroll
        for (int mi = 0; mi < MT; ++mi) {
            size_t off = (size_t)(arow + mi * 16 + lr) * lda + ka;
            ah[mi] = *(const short8*)(Ah + off);
            if (SPLIT) al[mi] = *(const short8*)(Al + off);
        }
        #pragma unroll
        for (int ni = 0; ni < NT_; ++ni) {
            size_t off = (size_t)(bcol + ni * 16 + lr) * ldb + ka;
            bh[ni] = *(const short8*)(Bh + off);
            if (SPLIT) bl[ni] = *(const short8*)(Bl + off);
        }
        #pragma unroll
        for (int mi = 0; mi < MT; ++mi)
            #pragma unroll
            for (int ni = 0; ni < NT_; ++ni) {
                acc[mi][ni] = __builtin_amdgcn_mfma_f32_16x16x32_bf16(ah[mi], bh[ni], acc[mi][ni], 0, 0, 0);
                if (SPLIT) {
                    acc[mi][ni] = __builtin_amdgcn_mfma_f32_16x16x32_bf16(ah[mi], bl[ni], acc[mi][ni], 0, 0, 0);
                    acc[mi][ni] = __builtin_amdgcn_mfma_f32_16x16x32_bf16(al[mi], bh[ni], acc[mi][ni], 0, 0, 0);
                }
            }
    }
}

// ============================================================
// K1 (merged): blocks [0,4096): RMSNorm + sigmoid gates (xn
// interleaved hi/lo). blocks [4096,4608): weight conversion.
// ============================================================
#define NQKV (3 * DIM * NH * DH)     // 786432 = 1536 rows x 512 k
#define NOUT (DIM * NH * DH)         // 262144
__global__ __launch_bounds__(256) void k_prep(
    const float* __restrict__ x, const float* __restrict__ gamma,
    const float* __restrict__ wg, const float* __restrict__ bg,
    const float* __restrict__ wqkv, const float* __restrict__ wout,
    unsigned short* __restrict__ xn_il, float* __restrict__ gates,
    unsigned short* __restrict__ wq_il, unsigned short* __restrict__ wout_b)
{
    int tid = threadIdx.x;
    if (blockIdx.x >= BS4 * NSEQ) {
        int base = (blockIdx.x - BS4 * NSEQ) * 2048;
        #pragma unroll
        for (int e = 0; e < 8; ++e) {
            int i = base + e * 256 + tid;
            if (i < NQKV) {
                unsigned short hh, ll;
                split2(wqkv[i], hh, ll);
                int row = i >> 9, k = i & 511;
                size_t a = (size_t)row * (2 * DIM) + il_addr(k);
                wq_il[a] = hh; wq_il[a + 8] = ll;
            } else {
                wout_b[i - NQKV] = f2bf(wout[i - NQKV]);
            }
        }
        return;
    }
    int r = blockIdx.x;
    const float* xr = x + (size_t)r * DIM;
    float v0 = xr[tid];
    float v1 = xr[tid + 256];
    float ss = v0 * v0 + v1 * v1;
    #pragma unroll
    for (int off = 32; off > 0; off >>= 1) ss += __shfl_down(ss, off, 64);
    __shared__ float sc[4];
    __shared__ float scw[NH][4];
    if ((tid & 63) == 0) sc[tid >> 6] = ss;
    __syncthreads();
    float tot = sc[0] + sc[1] + sc[2] + sc[3];
    float rs = rsqrtf(tot * (1.0f / DIM) + 1e-5f);
    float n0 = v0 * rs * gamma[tid];
    float n1 = v1 * rs * gamma[tid + 256];
    size_t rb = (size_t)r * (2 * DIM);
    unsigned short hh, ll;
    split2(n0, hh, ll);
    int a0 = il_addr(tid);
    xn_il[rb + a0] = hh; xn_il[rb + a0 + 8] = ll;
    split2(n1, hh, ll);
    int a1 = il_addr(tid + 256);
    xn_il[rb + a1] = hh; xn_il[rb + a1 + 8] = ll;
    #pragma unroll
    for (int h = 0; h < NH; ++h) {
        float p = n0 * wg[h * DIM + tid] + n1 * wg[h * DIM + tid + 256];
        #pragma unroll
        for (int off = 32; off > 0; off >>= 1) p += __shfl_down(p, off, 64);
        if ((tid & 63) == 0) scw[h][tid >> 6] = p;
    }
    __syncthreads();
    if (tid < NH) {
        float g = scw[tid][0] + scw[tid][1] + scw[tid][2] + scw[tid][3] + bg[tid];
        gates[(size_t)r * NH + tid] = 1.0f / (1.0f + __expf(-g));
    }
}

// ============================================================
// K2: QKV projection, split-bf16 MFMA (interleaved operands).
// 2-wave K-SPLIT blocks (128 thr): wave w accumulates K-half
// [w*256, w*256+256) (il layout -> pointer bump +512 ushorts).
// Combine via LDS; BOTH waves split the epilogue (q/k scatter by
// mi-half; v-path streams transposed straight from cls, no vs).
// Grid (24,64).
// ============================================================
__global__ __launch_bounds__(128) void k_qkv_mfma(
    const unsigned short* __restrict__ xn_il, const unsigned short* __restrict__ wq_il,
    unsigned short* __restrict__ q_il, unsigned short* __restrict__ k_il,
    unsigned short* __restrict__ vT_b)
{
    __shared__ float cls[64][68];
    int bx = blockIdx.x;
    int am = blockIdx.y * 64;
    int bn = bx * 64;
    int tid = threadIdx.x;
    int w = tid >> 6;
    int lane = tid & 63, lr = lane & 15, lq = lane >> 4;
    floatx4 acc[4][4];
    #pragma unroll
    for (int mi = 0; mi < 4; ++mi)
        #pragma unroll
        for (int ni = 0; ni < 4; ++ni) acc[mi][ni] = (floatx4){0.f, 0.f, 0.f, 0.f};
    // K-half per wave: elements [w*256, w*256+256); il offset = +w*512 ushorts
    mfma_nt_core<4, 4, true, true>(xn_il + w * 512, xn_il + w * 512 + 8,
                                   wq_il + w * 512, wq_il + w * 512 + 8,
                                   256, 2 * DIM, 2 * DIM, am, bn, acc);
    if (w == 1) {
        #pragma unroll
        for (int mi = 0; mi < 4; ++mi)
            #pragma unroll
            for (int ni = 0; ni < 4; ++ni)
                #pragma unroll
                for (int r = 0; r < 4; ++r)
                    cls[mi * 16 + lq * 4 + r][ni * 16 + lr] = acc[mi][ni][r];
    }
    __syncthreads();
    if (w == 0) {
        #pragma unroll
        for (int mi = 0; mi < 4; ++mi)
            #pragma unroll
            for (int ni = 0; ni < 4; ++ni)
                #pragma unroll
                for (int r = 0; r < 4; ++r)
                    cls[mi * 16 + lq * 4 + r][ni * 16 + lr] += acc[mi][ni][r];
    }
    __syncthreads();

    if (bx < 16) {
        // ---- q or k: interleaved hi/lo scatter, mi-half per wave ----
        const bool isq = (bx < 8);
        unsigned short* dst = isq ? q_il : k_il;
        const float scale = isq ? 8.0f : 1.0f;   // q * sqrt(dim_head)
        #pragma unroll
        for (int mi2 = 0; mi2 < 2; ++mi2) {
            int mi = w * 2 + mi2;
            #pragma unroll
            for (int ni = 0; ni < 4; ++ni)
                #pragma unroll
                for (int r = 0; r < 4; ++r) {
                    int row = am + mi * 16 + lq * 4 + r;
                    int col = bn + ni * 16 + lr;
                    int bs = row >> 10, npos = row & 1023;
                    int h = (col >> 6) & 7, d = col & 63;
                    size_t base = (((size_t)(bs * 8 + h)) * NSEQ + npos) * (2 * DH) + il_addr(d);
                    unsigned short hh, ll;
                    split2(cls[mi * 16 + lq * 4 + r][ni * 16 + lr] * scale, hh, ll);
                    dst[base] = hh; dst[base + 8] = ll;
                }
        }
    } else {
        // ---- v: stream transposed bf16 straight from cls ----
        const int h = bx - 16;
        const int bs = (blockIdx.y * 64) >> 10;
        const int bh = bs * 8 + h;
        const int npos_base = (blockIdx.y * 64) & 1023;
        #pragma unroll
        for (int it = 0; it < 4; ++it) {
            int d = it * 16 + (tid >> 3);        // 0..63 over 4 its x 128 thr
            int c8 = (tid & 7) * 8;              // npos sub-block
            alignas(16) unsigned short tmp[8];
            #pragma unroll
            for (int e = 0; e < 8; ++e) tmp[e] = f2bf(cls[c8 + e][d]);
            *(ulonglong2*)(vT_b + ((size_t)bh * DH + d) * NSEQ + npos_base + c8) = *(ulonglong2*)tmp;
        }
    }
}

// ============================================================
// K3: sim = q*k^T per bh, split-bf16 MFMA (interleaved operands),
// CAUSAL-TRIANGULAR: tiles with bn0 > am0+63 exit. 1-wave blocks.
// ============================================================
__global__ __launch_bounds__(64) void k_qk_mfma(
    const unsigned short* __restrict__ q_il, const unsigned short* __restrict__ k_il,
    float* __restrict__ sim_ws)
{
    __shared__ float cs[64][68];
    int am0 = blockIdx.y * 64;
    int bn0 = blockIdx.x * 64;
    if (bn0 > am0 + 63) return;
    int bh = blockIdx.z;
    int b_true = bh >> 4;
    int c = ((bh >> 3) & 1) * 8 + (bh & 7);
    const unsigned short* A = q_il + (size_t)bh * NSEQ * (2 * DH);
    const unsigned short* B = k_il + (size_t)bh * NSEQ * (2 * DH);
    floatx4 acc[4][4];
    #pragma unroll
    for (int mi = 0; mi < 4; ++mi)
        #pragma unroll
        for (int ni = 0; ni < 4; ++ni) acc[mi][ni] = (floatx4){0.f, 0.f, 0.f, 0.f};
    mfma_nt_core<4, 4, true, true>(A, A + 8, B, B + 8, DH, 2 * DH, 2 * DH, am0, bn0, acc);

    int tid = threadIdx.x;
    int lane = tid & 63, lr = lane & 15, lq = lane >> 4;
    #pragma unroll
    for (int mi = 0; mi < 4; ++mi)
        #pragma unroll
        for (int ni = 0; ni < 4; ++ni)
            #pragma unroll
            for (int r = 0; r < 4; ++r) {
                int lrow = mi * 16 + lq * 4 + r;
                int lcol = ni * 16 + lr;
                cs[lrow][lcol] = acc[mi][ni][r];
            }
    __syncthreads();
    int trow = tid >> 4;
    int tcol = (tid & 15) * 4;
    #pragma unroll
    for (int it = 0; it < 16; ++it) {
        int row = it * 4 + trow;
        float4 v4 = *(float4*)&cs[row][tcol];
        size_t gaddr = ((size_t)(b_true * NSEQ + am0 + row) * 16 + c) * NSEQ + bn0 + tcol;
        *(float4*)(sim_ws + gaddr) = v4;
    }
}

// ============================================================
// K4: pre-talk + mask + causal + softmax + post-talk.
// FROZEN r8 form (256 thr, thread owns 4 j, 16B accesses, 2
// barriers, attn2 in place over own sim row). Every alternative
// regressed: r3 pipelining, r4 causal-skip, r9 512-thr/occupancy.
// ============================================================
__global__ __launch_bounds__(256) void k_talk(
    float* __restrict__ sim_ws, const int* __restrict__ mask,
    const float* __restrict__ wpre, const float* __restrict__ wpost,
    float* __restrict__ probs_out)
{
    const int i = blockIdx.x;
    const int b = blockIdx.y;
    const int tid = threadIdx.x;
    const int wid = tid >> 6, lane = tid & 63;
    const int j0 = tid << 2;
    const size_t cstride = (size_t)NSEQ * NSEQ;
    float* simrow = sim_ws + (size_t)(b * NSEQ + i) * (16 * NSEQ);

    const int4 mi0 = *(const int4*)(mask + (size_t)(b * 2 + 0) * NSEQ + j0);
    const int4 mi1 = *(const int4*)(mask + (size_t)(b * 2 + 1) * NSEQ + j0);
    bool mb[2][4];
    mb[0][0] = (mi0.x != 0) && (j0 + 0 <= i);
    mb[0][1] = (mi0.y != 0) && (j0 + 1 <= i);
    mb[0][2] = (mi0.z != 0) && (j0 + 2 <= i);
    mb[0][3] = (mi0.w != 0) && (j0 + 3 <= i);
    mb[1][0] = (mi1.x != 0) && (j0 + 0 <= i);
    mb[1][1] = (mi1.y != 0) && (j0 + 1 <= i);
    mb[1][2] = (mi1.z != 0) && (j0 + 2 <= i);
    mb[1][3] = (mi1.w != 0) && (j0 + 3 <= i);

    // ---- pre talking-heads, c streamed outermost, packed j-pairs ----
    float2v val[16][2];
    #pragma unroll
    for (int o = 0; o < 16; ++o) {
        val[o][0] = (float2v){0.f, 0.f};
        val[o][1] = (float2v){0.f, 0.f};
    }
    #pragma unroll
    for (int c = 0; c < 16; ++c) {
        float4 r = *(const float4*)(simrow + c * NSEQ + j0);
        float2v r01 = (float2v){r.x, r.y};
        float2v r23 = (float2v){r.z, r.w};
        #pragma unroll
        for (int o = 0; o < 16; ++o) {
            float w = wpre[o * 16 + c];
            float2v wv = (float2v){w, w};
            val[o][0] = pk_fma(wv, r01, val[o][0]);
            val[o][1] = pk_fma(wv, r23, val[o][1]);
        }
    }
    #pragma unroll
    for (int o = 0; o < 16; ++o) {
        const int s = o >> 3;
        if (!mb[s][0]) val[o][0][0] = -FLT_MAX;
        if (!mb[s][1]) val[o][0][1] = -FLT_MAX;
        if (!mb[s][2]) val[o][1][0] = -FLT_MAX;
        if (!mb[s][3]) val[o][1][1] = -FLT_MAX;
    }

    __shared__ float red_m[16][4];
    __shared__ float red_s[16][4];

    // ---- wave max per o -> LDS (barrier 1) ----
    #pragma unroll
    for (int o = 0; o < 16; ++o) {
        float m = fmaxf(fmaxf(val[o][0][0], val[o][0][1]), fmaxf(val[o][1][0], val[o][1][1]));
        #pragma unroll
        for (int off = 32; off > 0; off >>= 1) m = fmaxf(m, __shfl_xor(m, off, 64));
        if (lane == 0) red_m[o][wid] = m;
    }
    __syncthreads();

    // ---- exp + wave sum per o -> LDS (barrier 2) ----
    #pragma unroll
    for (int o = 0; o < 16; ++o) {
        float mx = fmaxf(fmaxf(red_m[o][0], red_m[o][1]), fmaxf(red_m[o][2], red_m[o][3]));
        float e0 = __expf(val[o][0][0] - mx);
        float e1 = __expf(val[o][0][1] - mx);
        float e2 = __expf(val[o][1][0] - mx);
        float e3 = __expf(val[o][1][1] - mx);
        val[o][0][0] = e0; val[o][0][1] = e1;
        val[o][1][0] = e2; val[o][1][1] = e3;
        float s = (e0 + e1) + (e2 + e3);
        #pragma unroll
        for (int off = 32; off > 0; off >>= 1) s += __shfl_xor(s, off, 64);
        if (lane == 0) red_s[o][wid] = s;
    }
    __syncthreads();

    // ---- normalize + NT-store probs (output 1, [b*16+o][i][j]) ----
    #pragma unroll
    for (int o = 0; o < 16; ++o) {
        float inv = 1.0f / ((red_s[o][0] + red_s[o][1]) + (red_s[o][2] + red_s[o][3]));
        float2v invv = (float2v){inv, inv};
        val[o][0] *= invv;
        val[o][1] *= invv;
        floatx4 st = {val[o][0][0], val[o][0][1], val[o][1][0], val[o][1][1]};
        __builtin_nontemporal_store(st,
            (floatx4*)(probs_out + (size_t)(b * 16 + o) * cstride + (size_t)i * NSEQ + j0));
    }

    // ---- post talking-heads -> bf16 attn2, in place over own row ----
    unsigned short* a2row = (unsigned short*)simrow;
    #pragma unroll
    for (int o = 0; o < 16; ++o) {
        float2v a01 = (float2v){0.f, 0.f};
        float2v a23 = (float2v){0.f, 0.f};
        #pragma unroll
        for (int c = 0; c < 16; ++c) {
            float w = wpost[o * 16 + c];
            float2v wv = (float2v){w, w};
            a01 = pk_fma(wv, val[c][0], a01);
            a23 = pk_fma(wv, val[c][1], a23);
        }
        unsigned long long pk = (unsigned long long)f2bf(a01[0])
                              | ((unsigned long long)f2bf(a01[1]) << 16)
                              | ((unsigned long long)f2bf(a23[0]) << 32)
                              | ((unsigned long long)f2bf(a23[1]) << 48);
        *(unsigned long long*)(a2row + o * NSEQ + j0) = pk;
    }
}

// ============================================================
// K5: gated = (attn2 @ v) * gate, plain bf16 MFMA (NT with vT).
// 2-wave K-split blocks (128 thr); attn2 read from the interleaved
// sim_ws region (row stride 32768). FULL K=NSEQ (degenerate rows
// have mass beyond the diagonal — r5 lesson).
// ============================================================
__global__ __launch_bounds__(128) void k_av_mfma(
    const unsigned short* __restrict__ attn2_il, const unsigned short* __restrict__ vT_b,
    const float* __restrict__ gates, unsigned short* __restrict__ gated_b)
{
    __shared__ float cls[64][68];
    int bh = blockIdx.y;
    int bs = bh >> 3, h = bh & 7;
    int b_true = bh >> 4;
    int c = ((bh >> 3) & 1) * 8 + (bh & 7);
    int am = blockIdx.x * 64;
    int w = threadIdx.x >> 6;
    const unsigned short* Ah = attn2_il + (size_t)b_true * NSEQ * 32768 + (size_t)c * NSEQ + w * 512;
    const unsigned short* Bh = vT_b + (size_t)bh * DH * NSEQ + w * 512;
    floatx4 acc[4][4];
    #pragma unroll
    for (int mi = 0; mi < 4; ++mi)
        #pragma unroll
        for (int ni = 0; ni < 4; ++ni) acc[mi][ni] = (floatx4){0.f, 0.f, 0.f, 0.f};
    mfma_nt_core<4, 4, false, false>(Ah, nullptr, Bh, nullptr, 512, 32768, NSEQ, am, 0, acc);
    int lane = threadIdx.x & 63, lr = lane & 15, lq = lane >> 4;
    if (w == 1) {
        #pragma unroll
        for (int mi = 0; mi < 4; ++mi)
            #pragma unroll
            for (int ni = 0; ni < 4; ++ni)
                #pragma unroll
                for (int r = 0; r < 4; ++r)
                    cls[mi * 16 + lq * 4 + r][ni * 16 + lr] = acc[mi][ni][r];
    }
    __syncthreads();
    if (w == 0) {
        #pragma unroll
        for (int mi = 0; mi < 4; ++mi)
            #pragma unroll
            for (int ni = 0; ni < 4; ++ni)
                #pragma unroll
                for (int r = 0; r < 4; ++r) {
                    int i = am + mi * 16 + lq * 4 + r;
                    int d = ni * 16 + lr;
                    float v = acc[mi][ni][r] + cls[mi * 16 + lq * 4 + r][ni * 16 + lr];
                    float g = gates[((size_t)bs * NSEQ + i) * NH + h];
                    gated_b[((size_t)bs * NSEQ + i) * DIM + h * DH + d] = f2bf(v * g);
                }
    }
}

// ============================================================
// K6: out = gated @ wout^T, plain bf16 MFMA. 2-wave K-split
// blocks (128 thr), halves of K=512.
// ============================================================
__global__ __launch_bounds__(128) void k_out_mfma(
    const unsigned short* __restrict__ gated_b, const unsigned short* __restrict__ wout_b,
    float* __restrict__ out)
{
    __shared__ float cls[64][68];
    int am = blockIdx.y * 64;
    int bn = blockIdx.x * 64;
    int w = threadIdx.x >> 6;
    floatx4 acc[4][4];
    #pragma unroll
    for (int mi = 0; mi < 4; ++mi)
        #pragma unroll
        for (int ni = 0; ni < 4; ++ni) acc[mi][ni] = (floatx4){0.f, 0.f, 0.f, 0.f};
    mfma_nt_core<4, 4, false, false>(gated_b + w * 256, nullptr, wout_b + w * 256, nullptr,
                                     256, DIM, DIM, am, bn, acc);
    int lane = threadIdx.x & 63, lr = lane & 15, lq = lane >> 4;
    if (w == 1) {
        #pragma unroll
        for (int mi = 0; mi < 4; ++mi)
            #pragma unroll
            for (int ni = 0; ni < 4; ++ni)
                #pragma unroll
                for (int r = 0; r < 4; ++r)
                    cls[mi * 16 + lq * 4 + r][ni * 16 + lr] = acc[mi][ni][r];
    }
    __syncthreads();
    if (w == 0) {
        #pragma unroll
        for (int mi = 0; mi < 4; ++mi)
            #pragma unroll
            for (int ni = 0; ni < 4; ++ni)
                #pragma unroll
                for (int r = 0; r < 4; ++r) {
                    int row = am + mi * 16 + lq * 4 + r;
                    int col = bn + ni * 16 + lr;
                    out[(size_t)row * DIM + col] =
                        acc[mi][ni][r] + cls[mi * 16 + lq * 4 + r][ni * 16 + lr];
                }
    }
}

// ============================================================
extern "C" void kernel_launch(void* const* d_in, const int* in_sizes, int n_in,
                              void* d_out, int out_size, void* d_ws, size_t ws_size,
                              hipStream_t stream)
{
    (void)in_sizes; (void)n_in; (void)out_size; (void)ws_size;

    const float* x     = (const float*)d_in[0];
    const int*   mask  = (const int*)  d_in[1];
    const float* gamma = (const float*)d_in[2];
    const float* wqkv  = (const float*)d_in[3];
    const float* wg    = (const float*)d_in[4];
    const float* bg    = (const float*)d_in[5];
    const float* wpre  = (const float*)d_in[6];
    const float* wpost = (const float*)d_in[7];
    const float* wout  = (const float*)d_in[8];

    float* out       = (float*)d_out;
    float* probs_out = out + (size_t)BS4 * NSEQ * DIM;   // output 1: [bs][h][i][j]

    // workspace layout (bytes)
    char* ws = (char*)d_ws;
    unsigned short* xn_il   = (unsigned short*)(ws);                 //  8 MB  [4096][1024]
    unsigned short* wq_il   = (unsigned short*)(ws + 8388608);       //  3 MB  [1536][1024]
    unsigned short* wout_b  = (unsigned short*)(ws + 11534336);      //  0.5 MB
    float*          gates   = (float*)         (ws + 12058624);      //  128 KB
    unsigned short* q_il    = (unsigned short*)(ws + 12189696);      //  8 MB  [16][1024][128]
    unsigned short* k_il    = (unsigned short*)(ws + 20578304);      //  8 MB
    unsigned short* vT_b    = (unsigned short*)(ws + 28966912);      //  4 MB
    unsigned short* gated_b = (unsigned short*)(ws + 33161216);      //  4 MB
    float*          sim_ws  = (float*)         (ws + 37355520);      // 128 MB interleaved [b][i][c][j]

    k_prep<<<dim3(BS4 * NSEQ + 512), dim3(256), 0, stream>>>(
        x, gamma, wg, bg, wqkv, wout, xn_il, gates, wq_il, wout_b);
    k_qkv_mfma<<<dim3(24, 64), dim3(128), 0, stream>>>(xn_il, wq_il, q_il, k_il, vT_b);
    k_qk_mfma<<<dim3(16, 16, 32), dim3(64), 0, stream>>>(q_il, k_il, sim_ws);
    k_talk<<<dim3(NSEQ, B2), dim3(256), 0, stream>>>(sim_ws, mask, wpre, wpost, probs_out);
    k_av_mfma<<<dim3(16, 32), dim3(128), 0, stream>>>((unsigned short*)sim_ws, vT_b, gates, gated_b);
    k_out_mfma<<<dim3(8, 64), dim3(128), 0, stream>>>(gated_b, wout_b, out);
}

// Round 12
// 365.371 us; speedup vs baseline: 1.0341x; 1.0271x over previous
//
#include <hip/hip_runtime.h>
#include <cfloat>
#include <math.h>

#define B2   2
#define BS4  4
#define NH   8
#define DH   64
#define DIM  512
#define NSEQ 1024
#define AH   16

typedef __attribute__((ext_vector_type(8))) short short8;
typedef __attribute__((ext_vector_type(4))) float floatx4;
typedef __attribute__((ext_vector_type(2))) float float2v;

// ---------- bf16 helpers ----------
__device__ inline unsigned short f2bf(float x) {
    unsigned int u = __float_as_uint(x);
    unsigned int r = (u + 0x7fffu + ((u >> 16) & 1u)) >> 16;
    return (unsigned short)r;
}
__device__ inline float bf2f(unsigned short h) {
    return __uint_as_float(((unsigned int)h) << 16);
}
__device__ inline void split2(float x, unsigned short& h, unsigned short& l) {
    h = f2bf(x);
    l = f2bf(x - bf2f(h));
}
// interleaved hi/lo address within a row: element k -> (k/8)*16 + (k%8); lo at +8
__device__ inline int il_addr(int k) { return ((k >> 3) << 4) + (k & 7); }

// packed fp32 fma (v_pk_fma_f32 on gfx90a+/gfx950)
__device__ inline float2v pk_fma(float2v a, float2v b, float2v c) {
#if __has_builtin(__builtin_elementwise_fma)
    return __builtin_elementwise_fma(a, b, c);
#else
    float2v r;
    r[0] = fmaf(a[0], b[0], c[0]);
    r[1] = fmaf(a[1], b[1], c[1]);
    return r;
#endif
}

// ============================================================
// NT MFMA core: C[M,N] += A[M,K] * B[N,K]^T, bf16 frags.
// SPLIT=true: hi/lo pairs, 3 MFMAs (≈fp32 precision).
// IL=true: hi/lo interleaved per 8-elem chunk (row stride 2K,
// Al = Ah+8).
// ============================================================
template<int MT, int NT_, bool SPLIT, bool IL>
__device__ inline void mfma_nt_core(
    const unsigned short* __restrict__ Ah, const unsigned short* __restrict__ Al,
    const unsigned short* __restrict__ Bh, const unsigned short* __restrict__ Bl,
    int K, int lda, int ldb, int arow, int bcol, floatx4 acc[MT][NT_])
{
    int lane = threadIdx.x & 63;
    int lr = lane & 15, lq = lane >> 4;
    for (int k0 = 0; k0 < K; k0 += 32) {
        const int ka = IL ? (k0 + lq * 8) * 2 : (k0 + lq * 8);
        short8 ah[MT], al[MT], bh[NT_], bl[NT_];
        #pragma unroll
        for (int mi = 0; mi < MT; ++mi) {
            size_t off = (size_t)(arow + mi * 16 + lr) * lda + ka;
            ah[mi] = *(const short8*)(Ah + off);
            if (SPLIT) al[mi] = *(const short8*)(Al + off);
        }
        #pragma unroll
        for (int ni = 0; ni < NT_; ++ni) {
            size_t off = (size_t)(bcol + ni * 16 + lr) * ldb + ka;
            bh[ni] = *(const short8*)(Bh + off);
            if (SPLIT) bl[ni] = *(const short8*)(Bl + off);
        }
        #pragma unroll
        for (int mi = 0; mi < MT; ++mi)
            #pragma unroll
            for (int ni = 0; ni < NT_; ++ni) {
                acc[mi][ni] = __builtin_amdgcn_mfma_f32_16x16x32_bf16(ah[mi], bh[ni], acc[mi][ni], 0, 0, 0);
                if (SPLIT) {
                    acc[mi][ni] = __builtin_amdgcn_mfma_f32_16x16x32_bf16(ah[mi], bl[ni], acc[mi][ni], 0, 0, 0);
                    acc[mi][ni] = __builtin_amdgcn_mfma_f32_16x16x32_bf16(al[mi], bh[ni], acc[mi][ni], 0, 0, 0);
                }
            }
    }
}

// ============================================================
// K1 (merged): blocks [0,4096): RMSNorm + sigmoid gates (xn
// interleaved hi/lo). blocks [4096,4608): weight conversion.
// ============================================================
#define NQKV (3 * DIM * NH * DH)     // 786432 = 1536 rows x 512 k
#define NOUT (DIM * NH * DH)         // 262144
__global__ __launch_bounds__(256) void k_prep(
    const float* __restrict__ x, const float* __restrict__ gamma,
    const float* __restrict__ wg, const float* __restrict__ bg,
    const float* __restrict__ wqkv, const float* __restrict__ wout,
    unsigned short* __restrict__ xn_il, float* __restrict__ gates,
    unsigned short* __restrict__ wq_il, unsigned short* __restrict__ wout_b)
{
    int tid = threadIdx.x;
    if (blockIdx.x >= BS4 * NSEQ) {
        int base = (blockIdx.x - BS4 * NSEQ) * 2048;
        #pragma unroll
        for (int e = 0; e < 8; ++e) {
            int i = base + e * 256 + tid;
            if (i < NQKV) {
                unsigned short hh, ll;
                split2(wqkv[i], hh, ll);
                int row = i >> 9, k = i & 511;
                size_t a = (size_t)row * (2 * DIM) + il_addr(k);
                wq_il[a] = hh; wq_il[a + 8] = ll;
            } else {
                wout_b[i - NQKV] = f2bf(wout[i - NQKV]);
            }
        }
        return;
    }
    int r = blockIdx.x;
    const float* xr = x + (size_t)r * DIM;
    float v0 = xr[tid];
    float v1 = xr[tid + 256];
    float ss = v0 * v0 + v1 * v1;
    #pragma unroll
    for (int off = 32; off > 0; off >>= 1) ss += __shfl_down(ss, off, 64);
    __shared__ float sc[4];
    __shared__ float scw[NH][4];
    if ((tid & 63) == 0) sc[tid >> 6] = ss;
    __syncthreads();
    float tot = sc[0] + sc[1] + sc[2] + sc[3];
    float rs = rsqrtf(tot * (1.0f / DIM) + 1e-5f);
    float n0 = v0 * rs * gamma[tid];
    float n1 = v1 * rs * gamma[tid + 256];
    size_t rb = (size_t)r * (2 * DIM);
    unsigned short hh, ll;
    split2(n0, hh, ll);
    int a0 = il_addr(tid);
    xn_il[rb + a0] = hh; xn_il[rb + a0 + 8] = ll;
    split2(n1, hh, ll);
    int a1 = il_addr(tid + 256);
    xn_il[rb + a1] = hh; xn_il[rb + a1 + 8] = ll;
    #pragma unroll
    for (int h = 0; h < NH; ++h) {
        float p = n0 * wg[h * DIM + tid] + n1 * wg[h * DIM + tid + 256];
        #pragma unroll
        for (int off = 32; off > 0; off >>= 1) p += __shfl_down(p, off, 64);
        if ((tid & 63) == 0) scw[h][tid >> 6] = p;
    }
    __syncthreads();
    if (tid < NH) {
        float g = scw[tid][0] + scw[tid][1] + scw[tid][2] + scw[tid][3] + bg[tid];
        gates[(size_t)r * NH + tid] = 1.0f / (1.0f + __expf(-g));
    }
}

// ============================================================
// K2: QKV projection, split-bf16 MFMA (interleaved operands).
// 1-wave blocks (64 thr), 64x64 tile/wave. Grid (24,64).
// bx<8: q, 8..15: k (stores interleaved hi/lo, 32B-local),
// 16..23: v (LDS-staged transposed plain-bf16 epilogue).
// [r11 lesson: 2-wave K-split on this kernel was neutral-to-
// negative (366.6 -> 375.3); this 1-wave form is the optimum.]
// ============================================================
__global__ __launch_bounds__(64) void k_qkv_mfma(
    const unsigned short* __restrict__ xn_il, const unsigned short* __restrict__ wq_il,
    unsigned short* __restrict__ q_il, unsigned short* __restrict__ k_il,
    unsigned short* __restrict__ vT_b)
{
    __shared__ unsigned short vs[64][68];    // [d][npos_local], padded
    int bx = blockIdx.x;
    int am = blockIdx.y * 64;
    int bn = bx * 64;
    floatx4 acc[4][4];
    #pragma unroll
    for (int mi = 0; mi < 4; ++mi)
        #pragma unroll
        for (int ni = 0; ni < 4; ++ni) acc[mi][ni] = (floatx4){0.f, 0.f, 0.f, 0.f};
    mfma_nt_core<4, 4, true, true>(xn_il, xn_il + 8, wq_il, wq_il + 8,
                                   DIM, 2 * DIM, 2 * DIM, am, bn, acc);
    int tid = threadIdx.x;
    int lane = tid & 63, lr = lane & 15, lq = lane >> 4;

    if (bx < 16) {
        const bool isq = (bx < 8);
        unsigned short* dst = isq ? q_il : k_il;
        const float scale = isq ? 8.0f : 1.0f;   // q * sqrt(dim_head)
        #pragma unroll
        for (int mi = 0; mi < 4; ++mi)
            #pragma unroll
            for (int ni = 0; ni < 4; ++ni)
                #pragma unroll
                for (int r = 0; r < 4; ++r) {
                    int row = am + mi * 16 + lq * 4 + r;
                    int col = bn + ni * 16 + lr;
                    int bs = row >> 10, npos = row & 1023;
                    int h = (col >> 6) & 7, d = col & 63;
                    size_t base = (((size_t)(bs * 8 + h)) * NSEQ + npos) * (2 * DH) + il_addr(d);
                    unsigned short hh, ll;
                    split2(acc[mi][ni][r] * scale, hh, ll);
                    dst[base] = hh; dst[base + 8] = ll;
                }
    } else {
        const int h = bx - 16;
        const int bs = (blockIdx.y * 64) >> 10;
        const int bh = bs * 8 + h;
        const int npos_base = (blockIdx.y * 64) & 1023;
        #pragma unroll
        for (int mi = 0; mi < 4; ++mi)
            #pragma unroll
            for (int ni = 0; ni < 4; ++ni)
                #pragma unroll
                for (int r = 0; r < 4; ++r) {
                    int nl  = mi * 16 + lq * 4 + r;
                    int dl2 = ni * 16 + lr;
                    vs[dl2][nl] = f2bf(acc[mi][ni][r]);
                }
        __syncthreads();
        #pragma unroll
        for (int it = 0; it < 8; ++it) {
            int d = it * 8 + (tid >> 3);
            int c8 = (tid & 7) * 8;
            unsigned short* dst = vT_b + ((size_t)bh * DH + d) * NSEQ + npos_base + c8;
            *(ulonglong2*)dst = *(ulonglong2*)&vs[d][c8];
        }
    }
}

// ============================================================
// K3: sim = q*k^T per bh, split-bf16 MFMA (interleaved operands),
// CAUSAL-TRIANGULAR: tiles with bn0 > am0+63 exit. 1-wave blocks.
// ============================================================
__global__ __launch_bounds__(64) void k_qk_mfma(
    const unsigned short* __restrict__ q_il, const unsigned short* __restrict__ k_il,
    float* __restrict__ sim_ws)
{
    __shared__ float cs[64][68];
    int am0 = blockIdx.y * 64;
    int bn0 = blockIdx.x * 64;
    if (bn0 > am0 + 63) return;
    int bh = blockIdx.z;
    int b_true = bh >> 4;
    int c = ((bh >> 3) & 1) * 8 + (bh & 7);
    const unsigned short* A = q_il + (size_t)bh * NSEQ * (2 * DH);
    const unsigned short* B = k_il + (size_t)bh * NSEQ * (2 * DH);
    floatx4 acc[4][4];
    #pragma unroll
    for (int mi = 0; mi < 4; ++mi)
        #pragma unroll
        for (int ni = 0; ni < 4; ++ni) acc[mi][ni] = (floatx4){0.f, 0.f, 0.f, 0.f};
    mfma_nt_core<4, 4, true, true>(A, A + 8, B, B + 8, DH, 2 * DH, 2 * DH, am0, bn0, acc);

    int tid = threadIdx.x;
    int lane = tid & 63, lr = lane & 15, lq = lane >> 4;
    #pragma unroll
    for (int mi = 0; mi < 4; ++mi)
        #pragma unroll
        for (int ni = 0; ni < 4; ++ni)
            #pragma unroll
            for (int r = 0; r < 4; ++r) {
                int lrow = mi * 16 + lq * 4 + r;
                int lcol = ni * 16 + lr;
                cs[lrow][lcol] = acc[mi][ni][r];
            }
    __syncthreads();
    int trow = tid >> 4;
    int tcol = (tid & 15) * 4;
    #pragma unroll
    for (int it = 0; it < 16; ++it) {
        int row = it * 4 + trow;
        float4 v4 = *(float4*)&cs[row][tcol];
        size_t gaddr = ((size_t)(b_true * NSEQ + am0 + row) * 16 + c) * NSEQ + bn0 + tcol;
        *(float4*)(sim_ws + gaddr) = v4;
    }
}

// ============================================================
// K4: pre-talk + mask + causal + softmax + post-talk.
// FROZEN r8 form (256 thr, thread owns 4 j, 16B accesses, 2
// barriers, attn2 in place over own sim row). Every alternative
// regressed: r3 pipelining, r4 causal-skip, r9 512-thr/occupancy.
// ============================================================
__global__ __launch_bounds__(256) void k_talk(
    float* __restrict__ sim_ws, const int* __restrict__ mask,
    const float* __restrict__ wpre, const float* __restrict__ wpost,
    float* __restrict__ probs_out)
{
    const int i = blockIdx.x;
    const int b = blockIdx.y;
    const int tid = threadIdx.x;
    const int wid = tid >> 6, lane = tid & 63;
    const int j0 = tid << 2;
    const size_t cstride = (size_t)NSEQ * NSEQ;
    float* simrow = sim_ws + (size_t)(b * NSEQ + i) * (16 * NSEQ);

    const int4 mi0 = *(const int4*)(mask + (size_t)(b * 2 + 0) * NSEQ + j0);
    const int4 mi1 = *(const int4*)(mask + (size_t)(b * 2 + 1) * NSEQ + j0);
    bool mb[2][4];
    mb[0][0] = (mi0.x != 0) && (j0 + 0 <= i);
    mb[0][1] = (mi0.y != 0) && (j0 + 1 <= i);
    mb[0][2] = (mi0.z != 0) && (j0 + 2 <= i);
    mb[0][3] = (mi0.w != 0) && (j0 + 3 <= i);
    mb[1][0] = (mi1.x != 0) && (j0 + 0 <= i);
    mb[1][1] = (mi1.y != 0) && (j0 + 1 <= i);
    mb[1][2] = (mi1.z != 0) && (j0 + 2 <= i);
    mb[1][3] = (mi1.w != 0) && (j0 + 3 <= i);

    // ---- pre talking-heads, c streamed outermost, packed j-pairs ----
    float2v val[16][2];
    #pragma unroll
    for (int o = 0; o < 16; ++o) {
        val[o][0] = (float2v){0.f, 0.f};
        val[o][1] = (float2v){0.f, 0.f};
    }
    #pragma unroll
    for (int c = 0; c < 16; ++c) {
        float4 r = *(const float4*)(simrow + c * NSEQ + j0);
        float2v r01 = (float2v){r.x, r.y};
        float2v r23 = (float2v){r.z, r.w};
        #pragma unroll
        for (int o = 0; o < 16; ++o) {
            float w = wpre[o * 16 + c];
            float2v wv = (float2v){w, w};
            val[o][0] = pk_fma(wv, r01, val[o][0]);
            val[o][1] = pk_fma(wv, r23, val[o][1]);
        }
    }
    #pragma unroll
    for (int o = 0; o < 16; ++o) {
        const int s = o >> 3;
        if (!mb[s][0]) val[o][0][0] = -FLT_MAX;
        if (!mb[s][1]) val[o][0][1] = -FLT_MAX;
        if (!mb[s][2]) val[o][1][0] = -FLT_MAX;
        if (!mb[s][3]) val[o][1][1] = -FLT_MAX;
    }

    __shared__ float red_m[16][4];
    __shared__ float red_s[16][4];

    // ---- wave max per o -> LDS (barrier 1) ----
    #pragma unroll
    for (int o = 0; o < 16; ++o) {
        float m = fmaxf(fmaxf(val[o][0][0], val[o][0][1]), fmaxf(val[o][1][0], val[o][1][1]));
        #pragma unroll
        for (int off = 32; off > 0; off >>= 1) m = fmaxf(m, __shfl_xor(m, off, 64));
        if (lane == 0) red_m[o][wid] = m;
    }
    __syncthreads();

    // ---- exp + wave sum per o -> LDS (barrier 2) ----
    #pragma unroll
    for (int o = 0; o < 16; ++o) {
        float mx = fmaxf(fmaxf(red_m[o][0], red_m[o][1]), fmaxf(red_m[o][2], red_m[o][3]));
        float e0 = __expf(val[o][0][0] - mx);
        float e1 = __expf(val[o][0][1] - mx);
        float e2 = __expf(val[o][1][0] - mx);
        float e3 = __expf(val[o][1][1] - mx);
        val[o][0][0] = e0; val[o][0][1] = e1;
        val[o][1][0] = e2; val[o][1][1] = e3;
        float s = (e0 + e1) + (e2 + e3);
        #pragma unroll
        for (int off = 32; off > 0; off >>= 1) s += __shfl_xor(s, off, 64);
        if (lane == 0) red_s[o][wid] = s;
    }
    __syncthreads();

    // ---- normalize + NT-store probs (output 1, [b*16+o][i][j]) ----
    #pragma unroll
    for (int o = 0; o < 16; ++o) {
        float inv = 1.0f / ((red_s[o][0] + red_s[o][1]) + (red_s[o][2] + red_s[o][3]));
        float2v invv = (float2v){inv, inv};
        val[o][0] *= invv;
        val[o][1] *= invv;
        floatx4 st = {val[o][0][0], val[o][0][1], val[o][1][0], val[o][1][1]};
        __builtin_nontemporal_store(st,
            (floatx4*)(probs_out + (size_t)(b * 16 + o) * cstride + (size_t)i * NSEQ + j0));
    }

    // ---- post talking-heads -> bf16 attn2, in place over own row ----
    unsigned short* a2row = (unsigned short*)simrow;
    #pragma unroll
    for (int o = 0; o < 16; ++o) {
        float2v a01 = (float2v){0.f, 0.f};
        float2v a23 = (float2v){0.f, 0.f};
        #pragma unroll
        for (int c = 0; c < 16; ++c) {
            float w = wpost[o * 16 + c];
            float2v wv = (float2v){w, w};
            a01 = pk_fma(wv, val[c][0], a01);
            a23 = pk_fma(wv, val[c][1], a23);
        }
        unsigned long long pk = (unsigned long long)f2bf(a01[0])
                              | ((unsigned long long)f2bf(a01[1]) << 16)
                              | ((unsigned long long)f2bf(a23[0]) << 32)
                              | ((unsigned long long)f2bf(a23[1]) << 48);
        *(unsigned long long*)(a2row + o * NSEQ + j0) = pk;
    }
}

// ============================================================
// K5: gated = (attn2 @ v) * gate, plain bf16 MFMA (NT with vT).
// 2-wave K-split blocks (128 thr); attn2 read from the interleaved
// sim_ws region (row stride 32768). FULL K=NSEQ (degenerate rows
// have mass beyond the diagonal — r5 lesson).
// ============================================================
__global__ __launch_bounds__(128) void k_av_mfma(
    const unsigned short* __restrict__ attn2_il, const unsigned short* __restrict__ vT_b,
    const float* __restrict__ gates, unsigned short* __restrict__ gated_b)
{
    __shared__ float cls[64][68];
    int bh = blockIdx.y;
    int bs = bh >> 3, h = bh & 7;
    int b_true = bh >> 4;
    int c = ((bh >> 3) & 1) * 8 + (bh & 7);
    int am = blockIdx.x * 64;
    int w = threadIdx.x >> 6;
    const unsigned short* Ah = attn2_il + (size_t)b_true * NSEQ * 32768 + (size_t)c * NSEQ + w * 512;
    const unsigned short* Bh = vT_b + (size_t)bh * DH * NSEQ + w * 512;
    floatx4 acc[4][4];
    #pragma unroll
    for (int mi = 0; mi < 4; ++mi)
        #pragma unroll
        for (int ni = 0; ni < 4; ++ni) acc[mi][ni] = (floatx4){0.f, 0.f, 0.f, 0.f};
    mfma_nt_core<4, 4, false, false>(Ah, nullptr, Bh, nullptr, 512, 32768, NSEQ, am, 0, acc);
    int lane = threadIdx.x & 63, lr = lane & 15, lq = lane >> 4;
    if (w == 1) {
        #pragma unroll
        for (int mi = 0; mi < 4; ++mi)
            #pragma unroll
            for (int ni = 0; ni < 4; ++ni)
                #pragma unroll
                for (int r = 0; r < 4; ++r)
                    cls[mi * 16 + lq * 4 + r][ni * 16 + lr] = acc[mi][ni][r];
    }
    __syncthreads();
    if (w == 0) {
        #pragma unroll
        for (int mi = 0; mi < 4; ++mi)
            #pragma unroll
            for (int ni = 0; ni < 4; ++ni)
                #pragma unroll
                for (int r = 0; r < 4; ++r) {
                    int i = am + mi * 16 + lq * 4 + r;
                    int d = ni * 16 + lr;
                    float v = acc[mi][ni][r] + cls[mi * 16 + lq * 4 + r][ni * 16 + lr];
                    float g = gates[((size_t)bs * NSEQ + i) * NH + h];
                    gated_b[((size_t)bs * NSEQ + i) * DIM + h * DH + d] = f2bf(v * g);
                }
    }
}

// ============================================================
// K6: out = gated @ wout^T, plain bf16 MFMA. 2-wave K-split
// blocks (128 thr), halves of K=512.
// ============================================================
__global__ __launch_bounds__(128) void k_out_mfma(
    const unsigned short* __restrict__ gated_b, const unsigned short* __restrict__ wout_b,
    float* __restrict__ out)
{
    __shared__ float cls[64][68];
    int am = blockIdx.y * 64;
    int bn = blockIdx.x * 64;
    int w = threadIdx.x >> 6;
    floatx4 acc[4][4];
    #pragma unroll
    for (int mi = 0; mi < 4; ++mi)
        #pragma unroll
        for (int ni = 0; ni < 4; ++ni) acc[mi][ni] = (floatx4){0.f, 0.f, 0.f, 0.f};
    mfma_nt_core<4, 4, false, false>(gated_b + w * 256, nullptr, wout_b + w * 256, nullptr,
                                     256, DIM, DIM, am, bn, acc);
    int lane = threadIdx.x & 63, lr = lane & 15, lq = lane >> 4;
    if (w == 1) {
        #pragma unroll
        for (int mi = 0; mi < 4; ++mi)
            #pragma unroll
            for (int ni = 0; ni < 4; ++ni)
                #pragma unroll
                for (int r = 0; r < 4; ++r)
                    cls[mi * 16 + lq * 4 + r][ni * 16 + lr] = acc[mi][ni][r];
    }
    __syncthreads();
    if (w == 0) {
        #pragma unroll
        for (int mi = 0; mi < 4; ++mi)
            #pragma unroll
            for (int ni = 0; ni < 4; ++ni)
                #pragma unroll
                for (int r = 0; r < 4; ++r) {
                    int row = am + mi * 16 + lq * 4 + r;
                    int col = bn + ni * 16 + lr;
                    out[(size_t)row * DIM + col] =
                        acc[mi][ni][r] + cls[mi * 16 + lq * 4 + r][ni * 16 + lr];
                }
    }
}

// ============================================================
extern "C" void kernel_launch(void* const* d_in, const int* in_sizes, int n_in,
                              void* d_out, int out_size, void* d_ws, size_t ws_size,
                              hipStream_t stream)
{
    (void)in_sizes; (void)n_in; (void)out_size; (void)ws_size;

    const float* x     = (const float*)d_in[0];
    const int*   mask  = (const int*)  d_in[1];
    const float* gamma = (const float*)d_in[2];
    const float* wqkv  = (const float*)d_in[3];
    const float* wg    = (const float*)d_in[4];
    const float* bg    = (const float*)d_in[5];
    const float* wpre  = (const float*)d_in[6];
    const float* wpost = (const float*)d_in[7];
    const float* wout  = (const float*)d_in[8];

    float* out       = (float*)d_out;
    float* probs_out = out + (size_t)BS4 * NSEQ * DIM;   // output 1: [bs][h][i][j]

    // workspace layout (bytes)
    char* ws = (char*)d_ws;
    unsigned short* xn_il   = (unsigned short*)(ws);                 //  8 MB  [4096][1024]
    unsigned short* wq_il   = (unsigned short*)(ws + 8388608);       //  3 MB  [1536][1024]
    unsigned short* wout_b  = (unsigned short*)(ws + 11534336);      //  0.5 MB
    float*          gates   = (float*)         (ws + 12058624);      //  128 KB
    unsigned short* q_il    = (unsigned short*)(ws + 12189696);      //  8 MB  [16][1024][128]
    unsigned short* k_il    = (unsigned short*)(ws + 20578304);      //  8 MB
    unsigned short* vT_b    = (unsigned short*)(ws + 28966912);      //  4 MB
    unsigned short* gated_b = (unsigned short*)(ws + 33161216);      //  4 MB
    float*          sim_ws  = (float*)         (ws + 37355520);      // 128 MB interleaved [b][i][c][j]

    k_prep<<<dim3(BS4 * NSEQ + 512), dim3(256), 0, stream>>>(
        x, gamma, wg, bg, wqkv, wout, xn_il, gates, wq_il, wout_b);
    k_qkv_mfma<<<dim3(24, 64), dim3(64), 0, stream>>>(xn_il, wq_il, q_il, k_il, vT_b);
    k_qk_mfma<<<dim3(16, 16, 32), dim3(64), 0, stream>>>(q_il, k_il, sim_ws);
    k_talk<<<dim3(NSEQ, B2), dim3(256), 0, stream>>>(sim_ws, mask, wpre, wpost, probs_out);
    k_av_mfma<<<dim3(16, 32), dim3(128), 0, stream>>>((unsigned short*)sim_ws, vT_b, gates, gated_b);
    k_out_mfma<<<dim3(8, 64), dim3(128), 0, stream>>>(gated_b, wout_b, out);
}